// Round 3
// baseline (581.506 us; speedup 1.0000x reference)
//
#include <hip/hip_runtime.h>
#include <hip/hip_bf16.h>

#define BB 4
#define SS 512
#define DD 512
#define HH 8
#define DK 64
#define PP 16
#define TSZ 33   // 2P+1

typedef __bf16 bf16x8 __attribute__((ext_vector_type(8)));
typedef __bf16 bf16x4 __attribute__((ext_vector_type(4)));
typedef float  f32x4  __attribute__((ext_vector_type(4)));

__device__ inline bf16x8 cvt8(const float* __restrict__ p) {
    f32x4 a = *(const f32x4*)p;
    f32x4 b = *(const f32x4*)(p + 4);
    bf16x8 r;
    r[0] = (__bf16)a[0]; r[1] = (__bf16)a[1]; r[2] = (__bf16)a[2]; r[3] = (__bf16)a[3];
    r[4] = (__bf16)b[0]; r[5] = (__bf16)b[1]; r[6] = (__bf16)b[2]; r[7] = (__bf16)b[3];
    return r;
}

// ---------------- table mean ----------------
__global__ void tmean_kernel(const float* __restrict__ rel_table, float* __restrict__ Tm) {
    int t = threadIdx.x;
    if (t < TSZ) {
        float s = 0.f;
        for (int e = 0; e < DK; ++e) s += rel_table[t * DK + e];
        Tm[t] = s * (1.f / DK);
    }
}

// ---------------- QKV projection (MFMA), all three in one dispatch ----------------
// z=0: Q -> [b,h,s,dk]; z=1: K -> [b,h,s,dk]; z=2: V -> [b,h,dk,s] (transposed)
__global__ void proj_mfma_kernel(const float* __restrict__ X0, const float* __restrict__ X1,
                                 const float* __restrict__ X2,
                                 const float* __restrict__ W0, const float* __restrict__ W1,
                                 const float* __restrict__ W2,
                                 const float* __restrict__ B0, const float* __restrict__ B1,
                                 const float* __restrict__ B2,
                                 __bf16* __restrict__ O0, __bf16* __restrict__ O1,
                                 __bf16* __restrict__ O2) {
    int z = blockIdx.z;
    const float* X = (z == 0) ? X0 : (z == 1) ? X1 : X2;
    const float* W = (z == 0) ? W0 : (z == 1) ? W1 : W2;
    const float* bias = (z == 0) ? B0 : (z == 1) ? B1 : B2;
    __bf16* out = (z == 0) ? O0 : (z == 1) ? O1 : O2;
    int mode = (z == 2);

    int lane = threadIdx.x, wave = threadIdx.y;
    int tm = blockIdx.y * 4 + wave;   // 16-row tile [0,128)
    int tn = blockIdx.x;              // 16-col tile [0,32)
    int m = lane & 15, quad = lane >> 4;

    const float* arow = X + (size_t)(tm * 16 + m) * DD + quad * 8;
    const float* brow = W + (size_t)(tn * 16 + m) * DD + quad * 8;

    f32x4 acc = {0.f, 0.f, 0.f, 0.f};
    for (int k0 = 0; k0 < DD; k0 += 32) {
        bf16x8 a = cvt8(arow + k0);
        bf16x8 b = cvt8(brow + k0);
        acc = __builtin_amdgcn_mfma_f32_16x16x32_bf16(a, b, acc, 0, 0, 0);
    }

    int col = tn * 16 + m;
    int h = col >> 6, dk = col & (DK - 1);
    float bv = bias[col];
#pragma unroll
    for (int r = 0; r < 4; ++r) {
        int rowg = tm * 16 + quad * 4 + r;
        int b = rowg >> 9, i = rowg & (SS - 1);
        float v = acc[r] + bv;
        if (mode == 0)
            out[((size_t)(b * HH + h) * SS + i) * DK + dk] = (__bf16)v;
        else
            out[((size_t)(b * HH + h) * DK + dk) * SS + i] = (__bf16)v;
    }
}

// ---------------- F1: scores + relbias + partial softmax ----------------
// grid (jq=4, i0=32, b=4), block (64,8). wave w = head w for MFMA/softmax,
// rows {2w,2w+1} for bias compute.
__launch_bounds__(512, 2)
__global__ void f1_kernel(const __bf16* __restrict__ Qbf, const __bf16* __restrict__ Kbf,
                          const int* __restrict__ relpos, const float* __restrict__ Tm,
                          const int* __restrict__ mask, float* __restrict__ attn,
                          float* __restrict__ pm, float* __restrict__ pl) {
    __shared__ __bf16 tm_sh[16 * 16 * 72];   // [i][j][72], 64 d used
    __shared__ __bf16 qs_sh[8 * 17 * 72];    // [h][i(17)][72]
    __shared__ float  bias_sh[8 * 16 * 17];  // [h][i][17]
    __shared__ float  tmean_sh[TSZ];

    int l = threadIdx.x, w = threadIdx.y;
    int t = w * 64 + l;
    int jq = blockIdx.x, i0 = blockIdx.y, b = blockIdx.z;

    if (t < TSZ) tmean_sh[t] = Tm[t];

    // stage qs (all 8 heads, 16 rows, 64 d), bf16
    {
        int f = t * 16;
        int h = f >> 10, i = (f >> 6) & 15, d0 = f & 63;
        const __bf16* src = Qbf + ((size_t)(b * HH + h) * SS + i0 * 16 + i) * DK + d0;
        bf16x8 v0 = *(const bf16x8*)src;
        bf16x8 v1 = *(const bf16x8*)(src + 8);
        *(bf16x8*)&qs_sh[(h * 17 + i) * 72 + d0] = v0;
        *(bf16x8*)&qs_sh[(h * 17 + i) * 72 + d0 + 8] = v1;
    }

    // ---- phase A: scores, wave w = head w ----
    int m = l & 15, quad = l >> 4;
    const __bf16* qrow = Qbf + ((size_t)(b * HH + w) * SS + i0 * 16 + m) * DK + quad * 8;
    bf16x8 a0 = *(const bf16x8*)qrow;
    bf16x8 a1 = *(const bf16x8*)(qrow + 32);

    f32x4 acc[8];
#pragma unroll
    for (int jt = 0; jt < 8; ++jt) {
        const __bf16* krow = Kbf + ((size_t)(b * HH + w) * SS + jq * 128 + jt * 16 + m) * DK + quad * 8;
        bf16x8 b0 = *(const bf16x8*)krow;
        bf16x8 b1 = *(const bf16x8*)(krow + 32);
        f32x4 c = {0.f, 0.f, 0.f, 0.f};
        c = __builtin_amdgcn_mfma_f32_16x16x32_bf16(a0, b0, c, 0, 0, 0);
        c = __builtin_amdgcn_mfma_f32_16x16x32_bf16(a1, b1, c, 0, 0, 0);
        acc[jt] = c;
    }

    int h8 = l & 7, j8 = l >> 3;   // bias-compute lane roles

    // ---- phase B: bias per j-tile ----
    for (int jt = 0; jt < 8; ++jt) {
        __syncthreads();   // prior consume done / initial staging visible
        // stage tm tile [16i][16j][64d] -> bf16, via tmean gather
        const int* gidx = relpos + ((size_t)(b * SS + i0 * 16) * SS + jq * 128 + jt * 16) * DK;
#pragma unroll
        for (int c = 0; c < 8; ++c) {
            int f = c * 2048 + t * 4;
            int i = f >> 10, rem = f & 1023;        // rem = j*64 + d
            int4 v = *(const int4*)(gidx + (size_t)i * (SS * DK) + rem);
            int j = rem >> 6, d = rem & 63;
            int c0 = min(max(v.x, -PP), PP) + PP;
            int c1 = min(max(v.y, -PP), PP) + PP;
            int c2 = min(max(v.z, -PP), PP) + PP;
            int c3 = min(max(v.w, -PP), PP) + PP;
            bf16x4 pk = {(__bf16)tmean_sh[c0], (__bf16)tmean_sh[c1],
                         (__bf16)tmean_sh[c2], (__bf16)tmean_sh[c3]};
            *(bf16x4*)&tm_sh[(i * 16 + j) * 72 + d] = pk;
        }
        __syncthreads();
        // compute bias: lane (h8, j8), rows 2w, 2w+1
#pragma unroll
        for (int ii = 0; ii < 2; ++ii) {
            int i = w * 2 + ii;
#pragma unroll
            for (int half = 0; half < 2; ++half) {
                int j = j8 + 8 * half;
                float bacc = 0.f;
#pragma unroll
                for (int d8 = 0; d8 < 8; ++d8) {
                    bf16x8 tv = *(bf16x8*)&tm_sh[(i * 16 + j) * 72 + d8 * 8];
                    bf16x8 qv = *(bf16x8*)&qs_sh[(h8 * 17 + i) * 72 + d8 * 8];
#pragma unroll
                    for (int k = 0; k < 8; ++k) bacc += (float)tv[k] * (float)qv[k];
                }
                bias_sh[(h8 * 16 + i) * 17 + j] = bacc;
            }
        }
        __syncthreads();
        // consume into acc (wave w = head w), apply 1/sqrt(dk)
#pragma unroll
        for (int r = 0; r < 4; ++r)
            acc[jt][r] = acc[jt][r] * 0.125f + bias_sh[(w * 16 + quad * 4 + r) * 17 + m];
    }

    // ---- mask ----
#pragma unroll
    for (int jt = 0; jt < 8; ++jt) {
        int mv = mask[b * SS + jq * 128 + jt * 16 + m];
        if (mv == 0) {
#pragma unroll
            for (int r = 0; r < 4; ++r) acc[jt][r] = -1e9f;
        }
    }

    // ---- partial softmax over this quarter ----
#pragma unroll
    for (int r = 0; r < 4; ++r) {
        float mx = -1e30f;
#pragma unroll
        for (int jt = 0; jt < 8; ++jt) mx = fmaxf(mx, acc[jt][r]);
        mx = fmaxf(mx, __shfl_xor(mx, 1));
        mx = fmaxf(mx, __shfl_xor(mx, 2));
        mx = fmaxf(mx, __shfl_xor(mx, 4));
        mx = fmaxf(mx, __shfl_xor(mx, 8));
        float sum = 0.f;
#pragma unroll
        for (int jt = 0; jt < 8; ++jt) {
            float e = __expf(acc[jt][r] - mx);
            acc[jt][r] = e;
            sum += e;
        }
        sum += __shfl_xor(sum, 1);
        sum += __shfl_xor(sum, 2);
        sum += __shfl_xor(sum, 4);
        sum += __shfl_xor(sum, 8);
        if (m == 0) {
            int row = i0 * 16 + quad * 4 + r;
            pm[((size_t)(b * HH + w) * SS + row) * 4 + jq] = mx;
            pl[((size_t)(b * HH + w) * SS + row) * 4 + jq] = sum;
        }
    }

    // ---- store p' (unnormalized) ----
#pragma unroll
    for (int jt = 0; jt < 8; ++jt) {
#pragma unroll
        for (int r = 0; r < 4; ++r) {
            attn[((size_t)(b * HH + w) * SS + i0 * 16 + quad * 4 + r) * SS
                 + jq * 128 + jt * 16 + m] = acc[jt][r];
        }
    }
}

// ---------------- F2: normalize attn + ctx = P @ V ----------------
// grid (i0=32, bh=32), block 256
__launch_bounds__(256, 4)
__global__ void f2_kernel(float* __restrict__ attn, const float* __restrict__ pm,
                          const float* __restrict__ pl, const __bf16* __restrict__ Vt,
                          __bf16* __restrict__ ctx_bsd) {
    __shared__ float scl[4][16];
    __shared__ __bf16 p_sh[16 * 520];

    int t = threadIdx.x;
    int l = t & 63, wv = t >> 6;
    int i0 = blockIdx.x, bh = blockIdx.y;

    if (t < 16) {
        int row = i0 * 16 + t;
        float m0 = pm[((size_t)bh * SS + row) * 4 + 0];
        float m1 = pm[((size_t)bh * SS + row) * 4 + 1];
        float m2 = pm[((size_t)bh * SS + row) * 4 + 2];
        float m3 = pm[((size_t)bh * SS + row) * 4 + 3];
        float l0 = pl[((size_t)bh * SS + row) * 4 + 0];
        float l1 = pl[((size_t)bh * SS + row) * 4 + 1];
        float l2 = pl[((size_t)bh * SS + row) * 4 + 2];
        float l3 = pl[((size_t)bh * SS + row) * 4 + 3];
        float M = fmaxf(fmaxf(m0, m1), fmaxf(m2, m3));
        float e0 = __expf(m0 - M), e1 = __expf(m1 - M);
        float e2 = __expf(m2 - M), e3 = __expf(m3 - M);
        float L = l0 * e0 + l1 * e1 + l2 * e2 + l3 * e3;
        float inv = 1.f / L;
        scl[0][t] = e0 * inv; scl[1][t] = e1 * inv;
        scl[2][t] = e2 * inv; scl[3][t] = e3 * inv;
    }
    __syncthreads();

    float* arow = attn + ((size_t)bh * SS + i0 * 16) * SS;
#pragma unroll
    for (int rr = 0; rr < 4; ++rr) {
        int row = wv * 4 + rr;
#pragma unroll
        for (int it = 0; it < 2; ++it) {
            int col = it * 256 + l * 4;
            f32x4 v = *(f32x4*)(arow + (size_t)row * SS + col);
            float s = scl[col >> 7][row];
            v[0] *= s; v[1] *= s; v[2] *= s; v[3] *= s;
            *(f32x4*)(arow + (size_t)row * SS + col) = v;
            bf16x4 pk = {(__bf16)v[0], (__bf16)v[1], (__bf16)v[2], (__bf16)v[3]};
            *(bf16x4*)&p_sh[row * 520 + col] = pk;
        }
    }
    __syncthreads();

    // ctx: wave wv = d-tile wv (16 of 64)
    int m = l & 15, quad = l >> 4;
    f32x4 acc = {0.f, 0.f, 0.f, 0.f};
    const __bf16* vrow = Vt + ((size_t)bh * DK + wv * 16 + m) * SS + quad * 8;
    for (int k0 = 0; k0 < SS; k0 += 32) {
        bf16x8 aF = *(bf16x8*)&p_sh[m * 520 + k0 + quad * 8];
        bf16x8 bF = *(const bf16x8*)(vrow + k0);
        acc = __builtin_amdgcn_mfma_f32_16x16x32_bf16(aF, bF, acc, 0, 0, 0);
    }
    int b = bh >> 3, h = bh & 7;
#pragma unroll
    for (int r = 0; r < 4; ++r) {
        ctx_bsd[((size_t)(b * SS + i0 * 16 + quad * 4 + r)) * DD + h * DK + wv * 16 + m]
            = (__bf16)acc[r];
    }
}

// ---------------- x = ctx @ Wo^T + bo + query (MFMA), f32 out ----------------
__global__ void outproj_mfma_kernel(const __bf16* __restrict__ Xc, const float* __restrict__ Wo,
                                    const float* __restrict__ bo, const float* __restrict__ query,
                                    float* __restrict__ xres) {
    int lane = threadIdx.x, wave = threadIdx.y;
    int tm = blockIdx.y * 4 + wave;
    int tn = blockIdx.x;
    int m = lane & 15, quad = lane >> 4;

    const __bf16* arow = Xc + (size_t)(tm * 16 + m) * DD + quad * 8;
    const float*  brow = Wo + (size_t)(tn * 16 + m) * DD + quad * 8;

    f32x4 acc = {0.f, 0.f, 0.f, 0.f};
    for (int k0 = 0; k0 < DD; k0 += 32) {
        bf16x8 a = *(const bf16x8*)(arow + k0);
        bf16x8 b = cvt8(brow + k0);
        acc = __builtin_amdgcn_mfma_f32_16x16x32_bf16(a, b, acc, 0, 0, 0);
    }

    int col = tn * 16 + m;
    float bv = bo[col];
#pragma unroll
    for (int r = 0; r < 4; ++r) {
        int rowg = tm * 16 + quad * 4 + r;
        xres[(size_t)rowg * DD + col] = acc[r] + bv + query[(size_t)rowg * DD + col];
    }
}

// ---------------- LayerNorm over last dim (512) ----------------
__global__ void ln_kernel(const float* __restrict__ x, const float* __restrict__ gamma,
                          const float* __restrict__ beta, float* __restrict__ y) {
    int r = blockIdx.x;
    int t = threadIdx.x;
    float v0 = x[r * DD + t];
    float v1 = x[r * DD + t + 256];
    __shared__ float red[4];
    float s = v0 + v1;
#pragma unroll
    for (int off = 32; off >= 1; off >>= 1) s += __shfl_xor(s, off);
    if ((t & 63) == 0) red[t >> 6] = s;
    __syncthreads();
    float mu = (red[0] + red[1] + red[2] + red[3]) * (1.f / DD);
    __syncthreads();
    float d0 = v0 - mu, d1 = v1 - mu;
    float sq = d0 * d0 + d1 * d1;
#pragma unroll
    for (int off = 32; off >= 1; off >>= 1) sq += __shfl_xor(sq, off);
    if ((t & 63) == 0) red[t >> 6] = sq;
    __syncthreads();
    float var = (red[0] + red[1] + red[2] + red[3]) * (1.f / DD);
    float inv = rsqrtf(var + 1e-5f);
    y[r * DD + t] = d0 * inv * gamma[t] + beta[t];
    y[r * DD + t + 256] = d1 * inv * gamma[t + 256] + beta[t + 256];
}

extern "C" void kernel_launch(void* const* d_in, const int* in_sizes, int n_in,
                              void* d_out, int out_size, void* d_ws, size_t ws_size,
                              hipStream_t stream) {
    const float* query  = (const float*)d_in[0];
    const float* key    = (const float*)d_in[1];
    const float* value  = (const float*)d_in[2];
    const float* Wq     = (const float*)d_in[3];
    const float* bq     = (const float*)d_in[4];
    const float* Wk     = (const float*)d_in[5];
    const float* bk     = (const float*)d_in[6];
    const float* Wv     = (const float*)d_in[7];
    const float* bv     = (const float*)d_in[8];
    const float* Wo     = (const float*)d_in[9];
    const float* bo     = (const float*)d_in[10];
    const float* rtab   = (const float*)d_in[11];
    const float* gamma  = (const float*)d_in[12];
    const float* beta   = (const float*)d_in[13];
    const int*   mask   = (const int*)d_in[14];
    const int*   relpos = (const int*)d_in[15];

    float* out = (float*)d_out;
    float* y    = out;                        // [4,512,512]
    float* attn = out + (size_t)BB * SS * DD; // [4,8,512,512]

    char* wsb = (char*)d_ws;
    float*  Tm    = (float*)wsb;   wsb += 256;
    __bf16* Qbf   = (__bf16*)wsb;  wsb += (size_t)BB * HH * SS * DK * 2;
    __bf16* Kbf   = (__bf16*)wsb;  wsb += (size_t)BB * HH * SS * DK * 2;
    __bf16* Vtbf  = (__bf16*)wsb;  wsb += (size_t)BB * HH * DK * SS * 2;
    __bf16* ctxbf = (__bf16*)wsb;  wsb += (size_t)BB * SS * DD * 2;
    float*  xres  = (float*)wsb;   wsb += (size_t)BB * SS * DD * 4;
    float*  pm    = (float*)wsb;   wsb += (size_t)BB * HH * SS * 4 * 4;
    float*  pl    = (float*)wsb;   wsb += (size_t)BB * HH * SS * 4 * 4;

    hipLaunchKernelGGL(tmean_kernel, dim3(1), dim3(64), 0, stream, rtab, Tm);

    dim3 wblk(64, 4);
    hipLaunchKernelGGL(proj_mfma_kernel, dim3(DD / 16, (BB * SS) / 64, 3), wblk, 0, stream,
                       query, key, value, Wq, Wk, Wv, bq, bk, bv, Qbf, Kbf, Vtbf);

    hipLaunchKernelGGL(f1_kernel, dim3(4, SS / 16, BB), dim3(64, 8), 0, stream,
                       Qbf, Kbf, relpos, Tm, mask, attn, pm, pl);

    hipLaunchKernelGGL(f2_kernel, dim3(SS / 16, BB * HH), dim3(256), 0, stream,
                       attn, pm, pl, Vtbf, ctxbf);

    hipLaunchKernelGGL(outproj_mfma_kernel, dim3(DD / 16, (BB * SS) / 64), wblk, 0, stream,
                       ctxbf, Wo, bo, query, xres);

    hipLaunchKernelGGL(ln_kernel, dim3(BB * SS), dim3(256), 0, stream, xres, gamma, beta, y);
}

// Round 4
// 538.779 us; speedup vs baseline: 1.0793x; 1.0793x over previous
//
#include <hip/hip_runtime.h>
#include <hip/hip_bf16.h>

#define BB 4
#define SS 512
#define DD 512
#define HH 8
#define DK 64
#define PP 16
#define TSZ 33   // 2P+1

typedef __bf16 bf16x8 __attribute__((ext_vector_type(8)));
typedef __bf16 bf16x4 __attribute__((ext_vector_type(4)));
typedef float  f32x4  __attribute__((ext_vector_type(4)));

union U8 { bf16x8 v; int u[4]; };

__device__ inline bf16x8 cvt8(const float* __restrict__ p) {
    f32x4 a = *(const f32x4*)p;
    f32x4 b = *(const f32x4*)(p + 4);
    bf16x8 r;
    r[0] = (__bf16)a[0]; r[1] = (__bf16)a[1]; r[2] = (__bf16)a[2]; r[3] = (__bf16)a[3];
    r[4] = (__bf16)b[0]; r[5] = (__bf16)b[1]; r[6] = (__bf16)b[2]; r[7] = (__bf16)b[3];
    return r;
}

// ---------------- table mean ----------------
__global__ void tmean_kernel(const float* __restrict__ rel_table, float* __restrict__ Tm) {
    int t = threadIdx.x;
    if (t < TSZ) {
        float s = 0.f;
        for (int e = 0; e < DK; ++e) s += rel_table[t * DK + e];
        Tm[t] = s * (1.f / DK);
    }
}

// ---------------- QKV projection (MFMA), all three in one dispatch ----------------
__global__ void proj_mfma_kernel(const float* __restrict__ X0, const float* __restrict__ X1,
                                 const float* __restrict__ X2,
                                 const float* __restrict__ W0, const float* __restrict__ W1,
                                 const float* __restrict__ W2,
                                 const float* __restrict__ B0, const float* __restrict__ B1,
                                 const float* __restrict__ B2,
                                 __bf16* __restrict__ O0, __bf16* __restrict__ O1,
                                 __bf16* __restrict__ O2) {
    int z = blockIdx.z;
    const float* X = (z == 0) ? X0 : (z == 1) ? X1 : X2;
    const float* W = (z == 0) ? W0 : (z == 1) ? W1 : W2;
    const float* bias = (z == 0) ? B0 : (z == 1) ? B1 : B2;
    __bf16* out = (z == 0) ? O0 : (z == 1) ? O1 : O2;
    int mode = (z == 2);

    int lane = threadIdx.x, wave = threadIdx.y;
    int tm = blockIdx.y * 4 + wave;
    int tn = blockIdx.x;
    int m = lane & 15, quad = lane >> 4;

    const float* arow = X + (size_t)(tm * 16 + m) * DD + quad * 8;
    const float* brow = W + (size_t)(tn * 16 + m) * DD + quad * 8;

    f32x4 acc = {0.f, 0.f, 0.f, 0.f};
    for (int k0 = 0; k0 < DD; k0 += 32) {
        bf16x8 a = cvt8(arow + k0);
        bf16x8 b = cvt8(brow + k0);
        acc = __builtin_amdgcn_mfma_f32_16x16x32_bf16(a, b, acc, 0, 0, 0);
    }

    int col = tn * 16 + m;
    int h = col >> 6, dk = col & (DK - 1);
    float bv = bias[col];
#pragma unroll
    for (int r = 0; r < 4; ++r) {
        int rowg = tm * 16 + quad * 4 + r;
        int b = rowg >> 9, i = rowg & (SS - 1);
        float v = acc[r] + bv;
        if (mode == 0)
            out[((size_t)(b * HH + h) * SS + i) * DK + dk] = (__bf16)v;
        else
            out[((size_t)(b * HH + h) * DK + dk) * SS + i] = (__bf16)v;
    }
}

// ---------------- F1: scores + relbias(MFMA, reg-gather) + partial softmax ----------
// grid (jq=4, i0=32, b=4), block (64,8). wave w: head w for scores/softmax,
// j-tile w for bias. ONE barrier.
__launch_bounds__(512, 2)
__global__ void f1_kernel(const __bf16* __restrict__ Qbf, const __bf16* __restrict__ Kbf,
                          const int* __restrict__ relpos, const float* __restrict__ Tm,
                          const int* __restrict__ mask, float* __restrict__ attn,
                          float* __restrict__ pm, float* __restrict__ pl) {
    // bias_sh[h][i][j_local]: strides h:2112, i:132 (pad -> max 2-way bank alias)
    __shared__ float bias_sh[8 * 16 * 132];

    int l = threadIdx.x, w = threadIdx.y;
    int jq = blockIdx.x, i0 = blockIdx.y, b = blockIdx.z;
    int m = l & 15, quad = l >> 4;

    // Tmean as bf16 bits, register-resident (lanes 0..32)
    float tmf = Tm[l < TSZ ? l : 0];
    int tmb = (int)__builtin_bit_cast(unsigned short, (__bf16)tmf);

    // ---- bias phase: wave w handles local j-tile w, all h, i = 0..15 ----
    {
        const int ISTR = SS * DK; // 32768
        const int* rbase = relpos + ((size_t)(b * SS + i0 * 16) * SS + jq * 128 + w * 16 + m) * DK + quad * 8;
        int4 u0 = *(const int4*)(rbase);
        int4 u1 = *(const int4*)(rbase + 4);
        int4 u2 = *(const int4*)(rbase + 32);
        int4 u3 = *(const int4*)(rbase + 36);
        for (int i = 0; i < 16; ++i) {
            int4 n0, n1, n2, n3;
            if (i < 15) {
                const int* nb = rbase + (i + 1) * ISTR;
                n0 = *(const int4*)(nb);
                n1 = *(const int4*)(nb + 4);
                n2 = *(const int4*)(nb + 32);
                n3 = *(const int4*)(nb + 36);
            }
            // A-frags: Q[h=m&7, i, d]
            const __bf16* qp = Qbf + ((size_t)(b * HH + (m & 7)) * SS + i0 * 16 + i) * DK + quad * 8;
            bf16x8 A0 = *(const bf16x8*)qp;
            bf16x8 A1 = *(const bf16x8*)(qp + 32);
            // B-frags: Tm[clip(idx)] via bpermute LUT
#define LUT(vv) __builtin_amdgcn_ds_bpermute((min(max((vv), -PP), PP) + PP) << 2, tmb)
            U8 Bf0, Bf1;
            Bf0.u[0] = LUT(u0.x) | (LUT(u0.y) << 16);
            Bf0.u[1] = LUT(u0.z) | (LUT(u0.w) << 16);
            Bf0.u[2] = LUT(u1.x) | (LUT(u1.y) << 16);
            Bf0.u[3] = LUT(u1.z) | (LUT(u1.w) << 16);
            Bf1.u[0] = LUT(u2.x) | (LUT(u2.y) << 16);
            Bf1.u[1] = LUT(u2.z) | (LUT(u2.w) << 16);
            Bf1.u[2] = LUT(u3.x) | (LUT(u3.y) << 16);
            Bf1.u[3] = LUT(u3.z) | (LUT(u3.w) << 16);
#undef LUT
            f32x4 accB = {0.f, 0.f, 0.f, 0.f};
            accB = __builtin_amdgcn_mfma_f32_16x16x32_bf16(A0, Bf0.v, accB, 0, 0, 0);
            accB = __builtin_amdgcn_mfma_f32_16x16x32_bf16(A1, Bf1.v, accB, 0, 0, 0);
            if (quad < 2) {
#pragma unroll
                for (int r = 0; r < 4; ++r) {
                    int h = quad * 4 + r;   // 0..7
                    bias_sh[h * 2112 + i * 132 + w * 16 + m] = accB[r];
                }
            }
            u0 = n0; u1 = n1; u2 = n2; u3 = n3;
        }
    }

    // ---- score phase: wave w = head w ----
    const __bf16* qrow = Qbf + ((size_t)(b * HH + w) * SS + i0 * 16 + m) * DK + quad * 8;
    bf16x8 a0 = *(const bf16x8*)qrow;
    bf16x8 a1 = *(const bf16x8*)(qrow + 32);

    f32x4 acc[8];
#pragma unroll
    for (int jt = 0; jt < 8; ++jt) {
        const __bf16* krow = Kbf + ((size_t)(b * HH + w) * SS + jq * 128 + jt * 16 + m) * DK + quad * 8;
        bf16x8 b0 = *(const bf16x8*)krow;
        bf16x8 b1 = *(const bf16x8*)(krow + 32);
        f32x4 c = {0.f, 0.f, 0.f, 0.f};
        c = __builtin_amdgcn_mfma_f32_16x16x32_bf16(a0, b0, c, 0, 0, 0);
        c = __builtin_amdgcn_mfma_f32_16x16x32_bf16(a1, b1, c, 0, 0, 0);
        acc[jt] = c;
    }

    __syncthreads();   // bias_sh ready

    // ---- combine: scale + bias ----
#pragma unroll
    for (int jt = 0; jt < 8; ++jt) {
#pragma unroll
        for (int r = 0; r < 4; ++r) {
            float bv = bias_sh[w * 2112 + (quad * 4 + r) * 132 + jt * 16 + m];
            acc[jt][r] = acc[jt][r] * 0.125f + bv;
        }
    }

    // ---- mask ----
#pragma unroll
    for (int jt = 0; jt < 8; ++jt) {
        int mv = mask[b * SS + jq * 128 + jt * 16 + m];
        if (mv == 0) {
#pragma unroll
            for (int r = 0; r < 4; ++r) acc[jt][r] = -1e9f;
        }
    }

    // ---- partial softmax over this quarter ----
#pragma unroll
    for (int r = 0; r < 4; ++r) {
        float mx = -1e30f;
#pragma unroll
        for (int jt = 0; jt < 8; ++jt) mx = fmaxf(mx, acc[jt][r]);
        mx = fmaxf(mx, __shfl_xor(mx, 1));
        mx = fmaxf(mx, __shfl_xor(mx, 2));
        mx = fmaxf(mx, __shfl_xor(mx, 4));
        mx = fmaxf(mx, __shfl_xor(mx, 8));
        float sum = 0.f;
#pragma unroll
        for (int jt = 0; jt < 8; ++jt) {
            float e = __expf(acc[jt][r] - mx);
            acc[jt][r] = e;
            sum += e;
        }
        sum += __shfl_xor(sum, 1);
        sum += __shfl_xor(sum, 2);
        sum += __shfl_xor(sum, 4);
        sum += __shfl_xor(sum, 8);
        if (m == 0) {
            int row = i0 * 16 + quad * 4 + r;
            pm[((size_t)(b * HH + w) * SS + row) * 4 + jq] = mx;
            pl[((size_t)(b * HH + w) * SS + row) * 4 + jq] = sum;
        }
    }

    // ---- store p' (unnormalized) ----
#pragma unroll
    for (int jt = 0; jt < 8; ++jt) {
#pragma unroll
        for (int r = 0; r < 4; ++r) {
            attn[((size_t)(b * HH + w) * SS + i0 * 16 + quad * 4 + r) * SS
                 + jq * 128 + jt * 16 + m] = acc[jt][r];
        }
    }
}

// ---------------- F2: normalize attn + ctx = P @ V ----------------
__launch_bounds__(256, 4)
__global__ void f2_kernel(float* __restrict__ attn, const float* __restrict__ pm,
                          const float* __restrict__ pl, const __bf16* __restrict__ Vt,
                          __bf16* __restrict__ ctx_bsd) {
    __shared__ float scl[4][16];
    __shared__ __bf16 p_sh[16 * 520];

    int t = threadIdx.x;
    int l = t & 63, wv = t >> 6;
    int i0 = blockIdx.x, bh = blockIdx.y;

    if (t < 16) {
        int row = i0 * 16 + t;
        float m0 = pm[((size_t)bh * SS + row) * 4 + 0];
        float m1 = pm[((size_t)bh * SS + row) * 4 + 1];
        float m2 = pm[((size_t)bh * SS + row) * 4 + 2];
        float m3 = pm[((size_t)bh * SS + row) * 4 + 3];
        float l0 = pl[((size_t)bh * SS + row) * 4 + 0];
        float l1 = pl[((size_t)bh * SS + row) * 4 + 1];
        float l2 = pl[((size_t)bh * SS + row) * 4 + 2];
        float l3 = pl[((size_t)bh * SS + row) * 4 + 3];
        float M = fmaxf(fmaxf(m0, m1), fmaxf(m2, m3));
        float e0 = __expf(m0 - M), e1 = __expf(m1 - M);
        float e2 = __expf(m2 - M), e3 = __expf(m3 - M);
        float L = l0 * e0 + l1 * e1 + l2 * e2 + l3 * e3;
        float inv = 1.f / L;
        scl[0][t] = e0 * inv; scl[1][t] = e1 * inv;
        scl[2][t] = e2 * inv; scl[3][t] = e3 * inv;
    }
    __syncthreads();

    float* arow = attn + ((size_t)bh * SS + i0 * 16) * SS;
#pragma unroll
    for (int rr = 0; rr < 4; ++rr) {
        int row = wv * 4 + rr;
#pragma unroll
        for (int it = 0; it < 2; ++it) {
            int col = it * 256 + l * 4;
            f32x4 v = *(f32x4*)(arow + (size_t)row * SS + col);
            float s = scl[col >> 7][row];
            v[0] *= s; v[1] *= s; v[2] *= s; v[3] *= s;
            *(f32x4*)(arow + (size_t)row * SS + col) = v;
            bf16x4 pk = {(__bf16)v[0], (__bf16)v[1], (__bf16)v[2], (__bf16)v[3]};
            *(bf16x4*)&p_sh[row * 520 + col] = pk;
        }
    }
    __syncthreads();

    int m = l & 15, quad = l >> 4;
    f32x4 acc = {0.f, 0.f, 0.f, 0.f};
    const __bf16* vrow = Vt + ((size_t)bh * DK + wv * 16 + m) * SS + quad * 8;
    for (int k0 = 0; k0 < SS; k0 += 32) {
        bf16x8 aF = *(bf16x8*)&p_sh[m * 520 + k0 + quad * 8];
        bf16x8 bF = *(const bf16x8*)(vrow + k0);
        acc = __builtin_amdgcn_mfma_f32_16x16x32_bf16(aF, bF, acc, 0, 0, 0);
    }
    int b = bh >> 3, h = bh & 7;
#pragma unroll
    for (int r = 0; r < 4; ++r) {
        ctx_bsd[((size_t)(b * SS + i0 * 16 + quad * 4 + r)) * DD + h * DK + wv * 16 + m]
            = (__bf16)acc[r];
    }
}

// ---------------- x = ctx @ Wo^T + bo + query (MFMA), f32 out ----------------
__global__ void outproj_mfma_kernel(const __bf16* __restrict__ Xc, const float* __restrict__ Wo,
                                    const float* __restrict__ bo, const float* __restrict__ query,
                                    float* __restrict__ xres) {
    int lane = threadIdx.x, wave = threadIdx.y;
    int tm = blockIdx.y * 4 + wave;
    int tn = blockIdx.x;
    int m = lane & 15, quad = lane >> 4;

    const __bf16* arow = Xc + (size_t)(tm * 16 + m) * DD + quad * 8;
    const float*  brow = Wo + (size_t)(tn * 16 + m) * DD + quad * 8;

    f32x4 acc = {0.f, 0.f, 0.f, 0.f};
    for (int k0 = 0; k0 < DD; k0 += 32) {
        bf16x8 a = *(const bf16x8*)(arow + k0);
        bf16x8 b = cvt8(brow + k0);
        acc = __builtin_amdgcn_mfma_f32_16x16x32_bf16(a, b, acc, 0, 0, 0);
    }

    int col = tn * 16 + m;
    float bv = bo[col];
#pragma unroll
    for (int r = 0; r < 4; ++r) {
        int rowg = tm * 16 + quad * 4 + r;
        xres[(size_t)rowg * DD + col] = acc[r] + bv + query[(size_t)rowg * DD + col];
    }
}

// ---------------- LayerNorm over last dim (512) ----------------
__global__ void ln_kernel(const float* __restrict__ x, const float* __restrict__ gamma,
                          const float* __restrict__ beta, float* __restrict__ y) {
    int r = blockIdx.x;
    int t = threadIdx.x;
    float v0 = x[r * DD + t];
    float v1 = x[r * DD + t + 256];
    __shared__ float red[4];
    float s = v0 + v1;
#pragma unroll
    for (int off = 32; off >= 1; off >>= 1) s += __shfl_xor(s, off);
    if ((t & 63) == 0) red[t >> 6] = s;
    __syncthreads();
    float mu = (red[0] + red[1] + red[2] + red[3]) * (1.f / DD);
    __syncthreads();
    float d0 = v0 - mu, d1 = v1 - mu;
    float sq = d0 * d0 + d1 * d1;
#pragma unroll
    for (int off = 32; off >= 1; off >>= 1) sq += __shfl_xor(sq, off);
    if ((t & 63) == 0) red[t >> 6] = sq;
    __syncthreads();
    float var = (red[0] + red[1] + red[2] + red[3]) * (1.f / DD);
    float inv = rsqrtf(var + 1e-5f);
    y[r * DD + t] = d0 * inv * gamma[t] + beta[t];
    y[r * DD + t + 256] = d1 * inv * gamma[t + 256] + beta[t + 256];
}

extern "C" void kernel_launch(void* const* d_in, const int* in_sizes, int n_in,
                              void* d_out, int out_size, void* d_ws, size_t ws_size,
                              hipStream_t stream) {
    const float* query  = (const float*)d_in[0];
    const float* key    = (const float*)d_in[1];
    const float* value  = (const float*)d_in[2];
    const float* Wq     = (const float*)d_in[3];
    const float* bq     = (const float*)d_in[4];
    const float* Wk     = (const float*)d_in[5];
    const float* bk     = (const float*)d_in[6];
    const float* Wv     = (const float*)d_in[7];
    const float* bv     = (const float*)d_in[8];
    const float* Wo     = (const float*)d_in[9];
    const float* bo     = (const float*)d_in[10];
    const float* rtab   = (const float*)d_in[11];
    const float* gamma  = (const float*)d_in[12];
    const float* beta   = (const float*)d_in[13];
    const int*   mask   = (const int*)d_in[14];
    const int*   relpos = (const int*)d_in[15];

    float* out = (float*)d_out;
    float* y    = out;
    float* attn = out + (size_t)BB * SS * DD;

    char* wsb = (char*)d_ws;
    float*  Tm    = (float*)wsb;   wsb += 256;
    __bf16* Qbf   = (__bf16*)wsb;  wsb += (size_t)BB * HH * SS * DK * 2;
    __bf16* Kbf   = (__bf16*)wsb;  wsb += (size_t)BB * HH * SS * DK * 2;
    __bf16* Vtbf  = (__bf16*)wsb;  wsb += (size_t)BB * HH * DK * SS * 2;
    __bf16* ctxbf = (__bf16*)wsb;  wsb += (size_t)BB * SS * DD * 2;
    float*  xres  = (float*)wsb;   wsb += (size_t)BB * SS * DD * 4;
    float*  pm    = (float*)wsb;   wsb += (size_t)BB * HH * SS * 4 * 4;
    float*  pl    = (float*)wsb;   wsb += (size_t)BB * HH * SS * 4 * 4;

    hipLaunchKernelGGL(tmean_kernel, dim3(1), dim3(64), 0, stream, rtab, Tm);

    dim3 wblk(64, 4);
    hipLaunchKernelGGL(proj_mfma_kernel, dim3(DD / 16, (BB * SS) / 64, 3), wblk, 0, stream,
                       query, key, value, Wq, Wk, Wv, bq, bk, bv, Qbf, Kbf, Vtbf);

    hipLaunchKernelGGL(f1_kernel, dim3(4, SS / 16, BB), dim3(64, 8), 0, stream,
                       Qbf, Kbf, relpos, Tm, mask, attn, pm, pl);

    hipLaunchKernelGGL(f2_kernel, dim3(SS / 16, BB * HH), dim3(256), 0, stream,
                       attn, pm, pl, Vtbf, ctxbf);

    hipLaunchKernelGGL(outproj_mfma_kernel, dim3(DD / 16, (BB * SS) / 64), wblk, 0, stream,
                       ctxbf, Wo, bo, query, xres);

    hipLaunchKernelGGL(ln_kernel, dim3(BB * SS), dim3(256), 0, stream, xres, gamma, beta, y);
}